// Round 1
// baseline (457.983 us; speedup 1.0000x reference)
//
#include <hip/hip_runtime.h>

#define B_  32
#define L_  2048
#define H_  512
#define T_  2047      // L_-1 keys enter the scan
#define CC  16        // chunk size
#define NB  128       // ceil(T_/CC)
#define EPSF 1e-6f

// ---- wave64 sum reduction via DPP; full sum lands in lane 63 ----
template <int CTRL>
__device__ __forceinline__ float dpp_shift_add(float x) {
  int t = __builtin_amdgcn_update_dpp(0, __float_as_int(x), CTRL, 0xf, 0xf, true);
  return x + __int_as_float(t);
}
__device__ __forceinline__ float wave_reduce_lane63(float x) {
  x = dpp_shift_add<0x111>(x);  // row_shr:1
  x = dpp_shift_add<0x112>(x);  // row_shr:2
  x = dpp_shift_add<0x114>(x);  // row_shr:4
  x = dpp_shift_add<0x118>(x);  // row_shr:8
  x = dpp_shift_add<0x142>(x);  // row_bcast:15
  x = dpp_shift_add<0x143>(x);  // row_bcast:31
  return x;                     // valid in lane 63
}

// =====================================================================
// Kernel A: per (batch, chunk): Gram matrix, d vector, and
// TmT = transpose of (I + D^{-1} triu(G,1))^{-1} D^{-1}
// grid (NB, B_), 64 threads (1 wave). Lane owns 8 h-elements.
// =====================================================================
__global__ __launch_bounds__(64) void
deltarule_gram(const float* __restrict__ hidden,
               float* __restrict__ tmT, float* __restrict__ dvec) {
  const int cb   = blockIdx.x;
  const int b    = blockIdx.y;
  const int lane = threadIdx.x;
  __shared__ float G[CC * CC];

  const float* kb = hidden + ((size_t)b * L_ + (size_t)cb * CC) * H_;
  float kv[CC][8];
#pragma unroll
  for (int t = 0; t < CC; ++t) {
    if (cb * CC + t < T_) {
      float4 v0 = *(const float4*)(kb + (size_t)t * H_ + 4 * lane);
      float4 v1 = *(const float4*)(kb + (size_t)t * H_ + 256 + 4 * lane);
      kv[t][0] = v0.x; kv[t][1] = v0.y; kv[t][2] = v0.z; kv[t][3] = v0.w;
      kv[t][4] = v1.x; kv[t][5] = v1.y; kv[t][6] = v1.z; kv[t][7] = v1.w;
    } else {
#pragma unroll
      for (int u = 0; u < 8; ++u) kv[t][u] = 0.f;
    }
  }

  // pairwise dots (t <= s), wave-reduced, written by lane 63
#pragma unroll
  for (int t = 0; t < CC; ++t) {
#pragma unroll
    for (int s = t; s < CC; ++s) {
      float p = kv[t][0] * kv[s][0];
#pragma unroll
      for (int u = 1; u < 8; ++u) p = fmaf(kv[t][u], kv[s][u], p);
      p = wave_reduce_lane63(p);
      if (lane == 63) G[t * CC + s] = p;
    }
  }
  __syncthreads();

  // back-substitution: solve (I + D^{-1}U) X = D^{-1}; lane j holds column j
  float X[CC];
  const int j = lane;
#pragma unroll
  for (int t = CC - 1; t >= 0; --t) {
    float inner = 0.f;
#pragma unroll
    for (int s = t + 1; s < CC; ++s) inner = fmaf(G[t * CC + s], X[s], inner);
    float dt = G[t * CC + t] + EPSF;
    X[t] = (((j == t) ? 1.f : 0.f) - inner) / dt;
  }
  const size_t base = ((size_t)b * NB + cb) * (CC * CC);
  if (j < CC) {
#pragma unroll
    for (int u = 0; u < CC / 4; ++u)
      *(float4*)(tmT + base + j * CC + 4 * u) =
          make_float4(X[4 * u], X[4 * u + 1], X[4 * u + 2], X[4 * u + 3]);
  }
  if (lane < CC)
    dvec[((size_t)b * NB + cb) * CC + lane] = G[lane * CC + lane] + EPSF;
}

// =====================================================================
// Kernel B: backward chunked scan + fused output GEMM.
// grid (B_), 256 threads (4 waves). Thread owns h-elements {2*tid, 2*tid+1}.
// =====================================================================
__global__ __launch_bounds__(256) void
deltarule_scan(const float* __restrict__ hidden,
               const float* __restrict__ Wm, const float* __restrict__ bias,
               const float* __restrict__ tmT, const float* __restrict__ dvec,
               float* __restrict__ out) {
  const int b    = blockIdx.x;
  const int tid  = threadIdx.x;
  const int lane = tid & 63;
  const int wv   = tid >> 6;

  __shared__ float ldsTm[2 * CC * CC];
  __shared__ float ldsD[2 * CC];
  __shared__ float ldsPart[4 * CC];
  __shared__ float ldsY[CC];
  __shared__ float ldsSig[CC];
  __shared__ float ldsS[CC];
  __shared__ float ldsCtx[H_];

  const float* hb = hidden + (size_t)b * L_ * H_;
  float2 wq = *(const float2*)(hb + (size_t)(L_ - 1) * H_ + 2 * tid);
  float w0 = wq.x, w1 = wq.y;     // running w (query state)
  float c0 = 0.f, c1 = 0.f;       // context accumulator

  // preload chunk NB-1 keys + its Tm/d (into buffer (NB-1)&1 = 1)
  float k0[CC], k1[CC];
#pragma unroll
  for (int t = 0; t < CC; ++t) {
    if ((NB - 1) * CC + t < T_) {
      float2 v = *(const float2*)(hb + ((size_t)(NB - 1) * CC + t) * H_ + 2 * tid);
      k0[t] = v.x; k1[t] = v.y;
    } else { k0[t] = 0.f; k1[t] = 0.f; }
  }
  {
    const size_t tb = (size_t)b * NB + (NB - 1);
    ldsTm[((NB - 1) & 1) * CC * CC + tid] = tmT[tb * CC * CC + tid];
    if (tid < CC) ldsD[((NB - 1) & 1) * CC + tid] = dvec[tb * CC + tid];
  }
  __syncthreads();

  for (int c = NB - 1; c >= 0; --c) {
    const int buf = c & 1;

    // ---- prefetch chunk c-1 (keys to regs, Tm/d to regs; LDS store later) ----
    float kn0[CC], kn1[CC], tmN = 0.f, dN = 0.f;
    if (c > 0) {
      const float* kb = hb + ((size_t)(c - 1) * CC) * H_;
#pragma unroll
      for (int t = 0; t < CC; ++t) {   // c-1 <= 126: always in-bounds
        float2 v = *(const float2*)(kb + (size_t)t * H_ + 2 * tid);
        kn0[t] = v.x; kn1[t] = v.y;
      }
      const size_t tb = (size_t)b * NB + (c - 1);
      tmN = tmT[tb * CC * CC + tid];
      if (tid < CC) dN = dvec[tb * CC + tid];
    }

    // ---- y partials: p_t = k_t . w over this thread's 2 elements ----
    float red[CC];
#pragma unroll
    for (int t = 0; t < CC; ++t) {
      float p = fmaf(k0[t], w0, k1[t] * w1);
      red[t] = wave_reduce_lane63(p);
    }
    if (lane == 63) {
      float4* dst = (float4*)&ldsPart[wv * CC];
      dst[0] = make_float4(red[0], red[1], red[2], red[3]);
      dst[1] = make_float4(red[4], red[5], red[6], red[7]);
      dst[2] = make_float4(red[8], red[9], red[10], red[11]);
      dst[3] = make_float4(red[12], red[13], red[14], red[15]);
    }
    __syncthreads();   // barrier 1

    // ---- wave 0: finish y, solve sigma = Tm y, s = D sigma ----
    if (wv == 0) {
      if (lane < CC) {
        float y = ldsPart[lane] + ldsPart[CC + lane] +
                  ldsPart[2 * CC + lane] + ldsPart[3 * CC + lane];
        ldsY[lane] = y;
      }
      __asm__ volatile("s_waitcnt lgkmcnt(0)" ::: "memory");
      float4 ya = ((const float4*)ldsY)[0];
      float4 yb = ((const float4*)ldsY)[1];
      float4 yc = ((const float4*)ldsY)[2];
      float4 yd = ((const float4*)ldsY)[3];
      float yv[CC];
      yv[0]=ya.x; yv[1]=ya.y; yv[2]=ya.z; yv[3]=ya.w;
      yv[4]=yb.x; yv[5]=yb.y; yv[6]=yb.z; yv[7]=yb.w;
      yv[8]=yc.x; yv[9]=yc.y; yv[10]=yc.z; yv[11]=yc.w;
      yv[12]=yd.x; yv[13]=yd.y; yv[14]=yd.z; yv[15]=yd.w;
      if (lane < CC) {
        float sig = 0.f;
#pragma unroll
        for (int s = 0; s < CC; ++s)
          sig = fmaf(ldsTm[buf * CC * CC + s * CC + lane], yv[s], sig);
        ldsSig[lane] = sig;
        ldsS[lane]   = ldsD[buf * CC + lane] * sig;
      }
    }
    // other threads meanwhile stage next chunk's Tm/d into the other buffer
    if (c > 0) {
      ldsTm[(buf ^ 1) * CC * CC + tid] = tmN;
      if (tid < CC) ldsD[(buf ^ 1) * CC + tid] = dN;
    }
    __syncthreads();   // barrier 2

    // ---- rank-CC updates: w -= K^T sigma ; ctx += K^T s ----
    float4 g0 = ((const float4*)ldsSig)[0];
    float4 g1 = ((const float4*)ldsSig)[1];
    float4 g2 = ((const float4*)ldsSig)[2];
    float4 g3 = ((const float4*)ldsSig)[3];
    float4 s0 = ((const float4*)ldsS)[0];
    float4 s1 = ((const float4*)ldsS)[1];
    float4 s2 = ((const float4*)ldsS)[2];
    float4 s3 = ((const float4*)ldsS)[3];
    float sg[CC], sv[CC];
    sg[0]=g0.x; sg[1]=g0.y; sg[2]=g0.z; sg[3]=g0.w;
    sg[4]=g1.x; sg[5]=g1.y; sg[6]=g1.z; sg[7]=g1.w;
    sg[8]=g2.x; sg[9]=g2.y; sg[10]=g2.z; sg[11]=g2.w;
    sg[12]=g3.x; sg[13]=g3.y; sg[14]=g3.z; sg[15]=g3.w;
    sv[0]=s0.x; sv[1]=s0.y; sv[2]=s0.z; sv[3]=s0.w;
    sv[4]=s1.x; sv[5]=s1.y; sv[6]=s1.z; sv[7]=s1.w;
    sv[8]=s2.x; sv[9]=s2.y; sv[10]=s2.z; sv[11]=s2.w;
    sv[12]=s3.x; sv[13]=s3.y; sv[14]=s3.z; sv[15]=s3.w;
#pragma unroll
    for (int t = 0; t < CC; ++t) {
      w0 = fmaf(-sg[t], k0[t], w0);
      w1 = fmaf(-sg[t], k1[t], w1);
      c0 = fmaf(sv[t], k0[t], c0);
      c1 = fmaf(sv[t], k1[t], c1);
    }
    if (c > 0) {
#pragma unroll
      for (int t = 0; t < CC; ++t) { k0[t] = kn0[t]; k1[t] = kn1[t]; }
    }
  }

  // ---- epilogue: out[b] = W @ ctx + bias ----
  ldsCtx[2 * tid]     = c0;
  ldsCtx[2 * tid + 1] = c1;
  __syncthreads();
  const int j0 = tid, j1 = tid + 256;
  float acc0 = bias[j0], acc1 = bias[j1];
  const float* wr0 = Wm + (size_t)j0 * H_;
  const float* wr1 = Wm + (size_t)j1 * H_;
#pragma unroll 4
  for (int i = 0; i < H_; i += 4) {
    float4 cv = *(const float4*)&ldsCtx[i];
    float4 a0 = *(const float4*)(wr0 + i);
    float4 a1 = *(const float4*)(wr1 + i);
    acc0 += a0.x * cv.x + a0.y * cv.y + a0.z * cv.z + a0.w * cv.w;
    acc1 += a1.x * cv.x + a1.y * cv.y + a1.z * cv.z + a1.w * cv.w;
  }
  out[(size_t)b * H_ + j0] = acc0;
  out[(size_t)b * H_ + j1] = acc1;
}

// =====================================================================
extern "C" void kernel_launch(void* const* d_in, const int* in_sizes, int n_in,
                              void* d_out, int out_size, void* d_ws, size_t ws_size,
                              hipStream_t stream) {
  const float* hidden = (const float*)d_in[0];  // (32, 2048, 512) fp32
  const float* Wm     = (const float*)d_in[1];  // (512, 512) fp32
  const float* bias   = (const float*)d_in[2];  // (512,) fp32
  float* out = (float*)d_out;                   // (32, 512) fp32

  // workspace layout: TmT [B_*NB*CC*CC] | dvec [B_*NB*CC]
  float* tmT  = (float*)d_ws;
  float* dvec = tmT + (size_t)B_ * NB * CC * CC;

  dim3 gridA(NB, B_);
  deltarule_gram<<<gridA, 64, 0, stream>>>(hidden, tmT, dvec);
  deltarule_scan<<<B_, 256, 0, stream>>>(hidden, Wm, bias, tmT, dvec, out);
}

// Round 4
// 386.267 us; speedup vs baseline: 1.1857x; 1.1857x over previous
//
#include <hip/hip_runtime.h>

#define B_  32
#define L_  2048
#define H_  512
#define T_  2047      // L_-1 keys enter the scan
#define CA  32        // chunk size
#define NC  64        // chunks per batch (64*32 = 2048 >= 2047, last row padded)
#define EPSF 1e-6f

// ---- wave64 sum reduction via DPP; full sum lands in lane 63 ----
template <int CTRL>
__device__ __forceinline__ float dpp_shift_add(float x) {
  int t = __builtin_amdgcn_update_dpp(0, __float_as_int(x), CTRL, 0xf, 0xf, true);
  return x + __int_as_float(t);
}
__device__ __forceinline__ float wave_reduce_lane63(float x) {
  x = dpp_shift_add<0x111>(x);  // row_shr:1
  x = dpp_shift_add<0x112>(x);  // row_shr:2
  x = dpp_shift_add<0x114>(x);  // row_shr:4
  x = dpp_shift_add<0x118>(x);  // row_shr:8
  x = dpp_shift_add<0x142>(x);  // row_bcast:15
  x = dpp_shift_add<0x143>(x);  // row_bcast:31
  return x;                     // valid in lane 63
}

// async global->LDS, 16B per lane; LDS base must be wave-uniform
__device__ __forceinline__ void load_lds16(const float* g, float* l) {
  __builtin_amdgcn_global_load_lds(
      (const __attribute__((address_space(1))) unsigned int*)(g),
      (__attribute__((address_space(3))) unsigned int*)(l), 16, 0, 0);
}

// =====================================================================
// Kernel A: per (batch, chunk): Gram matrix G = K K^T, dvec = diag(G)+eps,
// and X = (I + D^{-1} triu(G,1))^{-1} D^{-1}.
// Lane j holds column j of X; stored contiguously: flat[j*32+s] = X[s][j].
// grid (NC, B_), 256 threads (4 waves). Wave w register-holds rows 8w..8w+7.
// =====================================================================
__global__ __launch_bounds__(256) void
deltarule_gram(const float* __restrict__ hidden,
               float* __restrict__ tmT, float* __restrict__ dvec) {
  const int cb = blockIdx.x, b = blockIdx.y;
  const int tid = threadIdx.x, lane = tid & 63, wv = tid >> 6;
  __shared__ __align__(16) float Kc[CA * H_];   // 64 KB, row-major contiguous
  __shared__ float G[CA * 33];                  // +1 pad

  const float* kb = hidden + ((size_t)b * L_ + (size_t)cb * CA) * H_;
#pragma unroll
  for (int u = 0; u < 16; ++u) {                // 16 issues x 4 waves = 64 segs
    const int off = (u * 4 + wv) * 256;         // 1 KB per wave-issue
    load_lds16(kb + off + 4 * lane, &Kc[off]);
  }
  __asm__ volatile("s_waitcnt vmcnt(0)" ::: "memory");
  __syncthreads();
  if (cb == NC - 1) {                           // zero padded key row 31
    if (tid < 128) *(float4*)&Kc[31 * H_ + 4 * tid] = make_float4(0.f, 0.f, 0.f, 0.f);
    __syncthreads();
  }

  // register rows: lane covers h in [4*lane,4*lane+4) u [256+4*lane, ...)
  float kr[8][8];
#pragma unroll
  for (int i = 0; i < 8; ++i) {
    const int r = 8 * wv + i;
    *(float4*)&kr[i][0] = *(const float4*)&Kc[r * H_ + 4 * lane];
    *(float4*)&kr[i][4] = *(const float4*)&Kc[r * H_ + 256 + 4 * lane];
  }
  float g[8] = {0.f, 0.f, 0.f, 0.f, 0.f, 0.f, 0.f, 0.f};  // lane j: G[row_i][j]
  for (int j = 8 * wv; j < CA; ++j) {           // only j >= first own row (symmetry)
    float kj[8];
    *(float4*)&kj[0] = *(const float4*)&Kc[j * H_ + 4 * lane];
    *(float4*)&kj[4] = *(const float4*)&Kc[j * H_ + 256 + 4 * lane];
#pragma unroll
    for (int i = 0; i < 8; ++i) {
      float p = kr[i][0] * kj[0];
#pragma unroll
      for (int u = 1; u < 8; ++u) p = fmaf(kr[i][u], kj[u], p);
      p = wave_reduce_lane63(p);
      float s = __int_as_float(__builtin_amdgcn_readlane(__float_as_int(p), 63));
      g[i] = (lane == j) ? s : g[i];            // select into lane j (s is SGPR)
    }
  }
  if (lane < CA) {
#pragma unroll
    for (int i = 0; i < 8; ++i) G[(8 * wv + i) * 33 + lane] = g[i];
  }
  __syncthreads();

  // back-substitution on wave 0: lane j = column j of X
  if (wv == 0) {
    const int j = lane & 31;
    float X[CA];
#pragma unroll
    for (int t = CA - 1; t >= 0; --t) {
      float inner = 0.f;
#pragma unroll
      for (int s = t + 1; s < CA; ++s) inner = fmaf(G[t * 33 + s], X[s], inner);
      X[t] = (((j == t) ? 1.f : 0.f) - inner) / (G[t * 33 + t] + EPSF);
    }
    if (lane < CA) {
      const size_t base = ((size_t)b * NC + cb) * (CA * CA);
      // flat[j*32 + s] = X[s][j]  (lane j's column stored contiguously)
#pragma unroll
      for (int u = 0; u < 8; ++u)
        *(float4*)&tmT[base + j * CA + 4 * u] =
            make_float4(X[4 * u], X[4 * u + 1], X[4 * u + 2], X[4 * u + 3]);
      dvec[((size_t)b * NC + cb) * CA + lane] = G[j * 33 + j] + EPSF;
    }
  }
}

// =====================================================================
// Kernel B: backward chunked scan + fused output GEMM.
// grid (B_), 512 threads (8 waves). Thread owns h = tid for updates;
// wave w owns key rows 4w..4w+3 for the dot phase (full row per wave).
// tmT layout from kernel A: flat[j*32+s] = X[s][j]  (column j contiguous).
// sigma[j] = (X y)[j] = sum_s X[j][s] y[s] = sum_s flat[s*32+j] y[s].
// Staged into padded LDS Tm[f>>5 *33 + (f&31)] => Tm[j*33+s] = X[s][j];
// solve reads Tm[s*33+j] = X[j][s] (consecutive j -> conflict-free).
// =====================================================================
__global__ __launch_bounds__(512) void
deltarule_scan(const float* __restrict__ hidden,
               const float* __restrict__ Wm, const float* __restrict__ bias,
               const float* __restrict__ tmT, const float* __restrict__ dvec,
               float* __restrict__ out) {
  const int b = blockIdx.x, tid = threadIdx.x, lane = tid & 63, wv = tid >> 6;
  __shared__ __align__(16) float Kc[2][CA * H_];  // 128 KB double buffer
  __shared__ float Tm[CA * 33];                   // single buffer (hazard-safe)
  __shared__ float Dv[CA];
  __shared__ float Yv[CA];
  __shared__ float2 SigS[CA];
  __shared__ __align__(16) float Wv[H_];
  __shared__ __align__(16) float Ctx[H_];

  const float* hb = hidden + (size_t)b * L_ * H_;
  float wh = hb[(size_t)(L_ - 1) * H_ + tid];     // running w, own element
  Wv[tid] = wh;
  float ch = 0.f;                                 // context accumulator

  // ---- stage chunk NC-1 (keys + Tm + D) ----
  {
    const float* kb = hb + (size_t)(NC - 1) * CA * H_;
#pragma unroll
    for (int u = 0; u < 8; ++u) {                 // 8 issues x 8 waves = 64 segs
      const int off = (u * 8 + wv) * 256;
      load_lds16(kb + off + 4 * lane, &Kc[1][off]);
    }
    const size_t tb = (size_t)b * NC + (NC - 1);
    float2 t2 = *(const float2*)&tmT[tb * (CA * CA) + 2 * tid];
    const int e0 = 2 * tid;
    Tm[(e0 >> 5) * 33 + (e0 & 31)] = t2.x;
    Tm[((e0 + 1) >> 5) * 33 + ((e0 + 1) & 31)] = t2.y;
    if (tid < CA) Dv[tid] = dvec[tb * CA + tid];
  }
  __asm__ volatile("s_waitcnt vmcnt(0)" ::: "memory");
  __syncthreads();
  // zero padded key row 31 of the tail chunk (it loaded real row 2047)
  if (tid < 128) *(float4*)&Kc[1][31 * H_ + 4 * tid] = make_float4(0.f, 0.f, 0.f, 0.f);
  __syncthreads();

  for (int c = NC - 1; c >= 0; --c) {
    const int buf = c & 1;

    // ---- prefetch chunk c-1: Tm/D to regs FIRST (so their wait doesn't
    //      drain the async K staging), then async K -> LDS buf^1 ----
    float2 tmN = make_float2(0.f, 0.f); float dN = 0.f;
    if (c > 0) {
      const size_t tb = (size_t)b * NC + (c - 1);
      tmN = *(const float2*)&tmT[tb * (CA * CA) + 2 * tid];
      if (tid < CA) dN = dvec[tb * CA + tid];
      const float* kb = hb + (size_t)(c - 1) * CA * H_;
#pragma unroll
      for (int u = 0; u < 8; ++u) {               // 8 issues x 8 waves = 64 segs
        const int off = (u * 8 + wv) * 256;
        load_lds16(kb + off + 4 * lane, &Kc[buf ^ 1][off]);
      }
    }

    // ---- dot phase: wave wv computes y for rows 4wv..4wv+3 ----
    {
      float4 wa = *(const float4*)&Wv[4 * lane];
      float4 wb = *(const float4*)&Wv[256 + 4 * lane];
#pragma unroll
      for (int i = 0; i < 4; ++i) {
        const int r = 4 * wv + i;
        float4 ka = *(const float4*)&Kc[buf][r * H_ + 4 * lane];
        float4 kc = *(const float4*)&Kc[buf][r * H_ + 256 + 4 * lane];
        float p = ka.x * wa.x;
        p = fmaf(ka.y, wa.y, p); p = fmaf(ka.z, wa.z, p); p = fmaf(ka.w, wa.w, p);
        p = fmaf(kc.x, wb.x, p); p = fmaf(kc.y, wb.y, p);
        p = fmaf(kc.z, wb.z, p); p = fmaf(kc.w, wb.w, p);
        p = wave_reduce_lane63(p);
        if (lane == 63) Yv[r] = p;
      }
    }
    __syncthreads();  // b1: Yv visible

    // ---- solve on wave 0: sigma[j] = sum_s Tm[s*33+j] * y[s]; s = D*sigma
    if (wv == 0) {
      const int j = lane & 31, hf = lane >> 5;
      float sig = 0.f;
#pragma unroll
      for (int s0 = 0; s0 < 16; ++s0) {
        const int s = hf * 16 + s0;
        sig = fmaf(Tm[s * 33 + j], Yv[s], sig);
      }
      sig += __shfl_down(sig, 32);
      if (lane < CA) SigS[j] = make_float2(sig, Dv[j] * sig);
    }
    __syncthreads();  // b2: SigS visible; Tm/Dv reads done

    // stage next chunk's Tm/D (single buffer: safe between b2 and b3)
    if (c > 0) {
      const int e0 = 2 * tid;
      Tm[(e0 >> 5) * 33 + (e0 & 31)] = tmN.x;
      Tm[((e0 + 1) >> 5) * 33 + ((e0 + 1) & 31)] = tmN.y;
      if (tid < CA) Dv[tid] = dN;
    }

    // ---- update: w -= K^T sigma ; ctx += K^T s  (h-parallel, h = tid) ----
#pragma unroll
    for (int t = 0; t < CA; ++t) {
      float2 ss = SigS[t];                 // broadcast
      float kvv = Kc[buf][t * H_ + tid];   // conflict-free column read
      wh = fmaf(-ss.x, kvv, wh);
      ch = fmaf(ss.y, kvv, ch);
    }
    Wv[tid] = wh;
    __asm__ volatile("s_waitcnt vmcnt(0)" ::: "memory");  // K prefetch done
    __syncthreads();  // b3
  }

  // ---- epilogue: out[b] = W @ ctx + bias ----
  Ctx[tid] = ch;
  __syncthreads();
  float acc = bias[tid];
  const float* wr = Wm + (size_t)tid * H_;
#pragma unroll 8
  for (int i = 0; i < H_; i += 4) {
    float4 w4 = *(const float4*)(wr + i);
    float4 cv = *(const float4*)&Ctx[i];
    acc = fmaf(w4.x, cv.x, acc); acc = fmaf(w4.y, cv.y, acc);
    acc = fmaf(w4.z, cv.z, acc); acc = fmaf(w4.w, cv.w, acc);
  }
  out[(size_t)b * H_ + tid] = acc;
}

// =====================================================================
extern "C" void kernel_launch(void* const* d_in, const int* in_sizes, int n_in,
                              void* d_out, int out_size, void* d_ws, size_t ws_size,
                              hipStream_t stream) {
  const float* hidden = (const float*)d_in[0];  // (32, 2048, 512) fp32
  const float* Wm     = (const float*)d_in[1];  // (512, 512) fp32
  const float* bias   = (const float*)d_in[2];  // (512,) fp32
  float* out = (float*)d_out;                   // (32, 512) fp32

  // workspace: tmT [B_*NC*CA*CA] floats (8 MB) | dvec [B_*NC*CA] floats
  float* tmT  = (float*)d_ws;
  float* dvec = tmT + (size_t)B_ * NC * CA * CA;

  dim3 gridA(NC, B_);
  deltarule_gram<<<gridA, 256, 0, stream>>>(hidden, tmT, dvec);
  deltarule_scan<<<B_, 512, 0, stream>>>(hidden, Wm, bias, tmT, dvec, out);
}